// Round 9
// baseline (880.273 us; speedup 1.0000x reference)
//
#include <hip/hip_runtime.h>
#include <math.h>

#define NPAIR 80      // B*QPV = 16*5
#define SEQV  2048
#define SEQQ  32
#define VDIM  768
#define QDIM  768
#define HID   512
#define HID2  1024
#define OUTC  5
#define NCHUNK 16
#define CHUNK  128    // SEQV / NCHUNK

// ---------------------------------------------------------------------------
// pre_kernel: one block (1024 thr = 16 waves) per (b,q) pair. Entire chain:
//   qvec = Wqp @ q + bqp ; qq = Wq @ qvec ; wk = Wk^T @ qq ;
//   weff = scale * Wvp^T @ wk ; sbias = scale * bvp . wk
// ---------------------------------------------------------------------------
__global__ __launch_bounds__(1024) void pre_kernel(
    const float* __restrict__ ques, const float* __restrict__ Wqp,
    const float* __restrict__ bqp,  const float* __restrict__ Wq,
    const float* __restrict__ Wk,   const float* __restrict__ Wvp,
    const float* __restrict__ bvp,
    float* __restrict__ qvec_out, float* __restrict__ weff_out,
    float* __restrict__ sbias_out)
{
    __shared__ float s_q[QDIM];     // ques row, later reused as scratch
    __shared__ float s_qvec[HID];
    __shared__ float s_qq[HID2];
    __shared__ float s_wk[HID];

    const int p    = blockIdx.x;
    const int t    = threadIdx.x;
    const int wave = t >> 6;
    const int lane = t & 63;
    const float scale = 0.03125f;   // 1/sqrt(1024)

    const float* qrow = ques + (size_t)p * SEQQ * QDIM;   // seq position 0
    for (int i = t; i < QDIM; i += 1024) s_q[i] = qrow[i];
    __syncthreads();

    // qvec: 512 rows x dot768 (wave-per-row, float4)
    for (int row = wave; row < HID; row += 16) {
        const float4* w4 = (const float4*)(Wqp + (size_t)row * QDIM);
        const float4* q4 = (const float4*)s_q;
        float acc = 0.f;
#pragma unroll
        for (int j = 0; j < 3; ++j) {
            float4 w = w4[lane + 64 * j], q = q4[lane + 64 * j];
            acc += w.x * q.x + w.y * q.y + w.z * q.z + w.w * q.w;
        }
#pragma unroll
        for (int off = 32; off; off >>= 1) acc += __shfl_xor(acc, off);
        if (lane == 0) s_qvec[row] = acc + bqp[row];
    }
    __syncthreads();

    for (int i = t; i < HID; i += 1024) qvec_out[p * HID + i] = s_qvec[i];

    // qq: 1024 rows x dot512
    for (int row = wave; row < HID2; row += 16) {
        const float4* w4 = (const float4*)(Wq + (size_t)row * HID);
        const float4* q4 = (const float4*)s_qvec;
        float acc = 0.f;
#pragma unroll
        for (int j = 0; j < 2; ++j) {
            float4 w = w4[lane + 64 * j], q = q4[lane + 64 * j];
            acc += w.x * q.x + w.y * q.y + w.z * q.z + w.w * q.w;
        }
#pragma unroll
        for (int off = 32; off; off >>= 1) acc += __shfl_xor(acc, off);
        if (lane == 0) s_qq[row] = acc;
    }
    __syncthreads();

    // wk[h] = sum_kk Wk[kk,h] * qq[kk]  (coalesced over h; kk split in halves)
    {
        const int h    = t & (HID - 1);
        const int half = t >> 9;          // 0 or 1
        const int kk0  = half * (HID2 / 2);
        float a0 = 0.f, a1 = 0.f;
        for (int kk = kk0; kk < kk0 + HID2 / 2; kk += 2) {
            a0 += Wk[(size_t)kk * HID + h] * s_qq[kk];
            a1 += Wk[(size_t)(kk + 1) * HID + h] * s_qq[kk + 1];
        }
        if (half == 1) s_q[h] = a0 + a1;   // s_q reused as scratch
        __syncthreads();
        if (half == 0) s_wk[h] = a0 + a1 + s_q[h];
    }
    __syncthreads();

    // weff[d] = scale * sum_h Wvp[h,d] * wk[h]  (coalesced over d)
    if (t < VDIM) {
        float a0 = 0.f, a1 = 0.f;
        for (int h = 0; h < HID; h += 2) {
            a0 += Wvp[(size_t)h * VDIM + t] * s_wk[h];
            a1 += Wvp[(size_t)(h + 1) * VDIM + t] * s_wk[h + 1];
        }
        weff_out[p * VDIM + t] = (a0 + a1) * scale;
    }
    // sbias (wave 15: t in [960,1024), disjoint from weff threads)
    if (wave == 15) {
        float acc = 0.f;
        for (int h = lane; h < HID; h += 64) acc += bvp[h] * s_wk[h];
#pragma unroll
        for (int off = 32; off; off >>= 1) acc += __shfl_xor(acc, off);
        if (lane == 0) sbias_out[p] = acc * scale;
    }
}

// ---------------------------------------------------------------------------
// flash_kernel (unchanged, measured-null vs v2 => HBM-bound): fused score +
// online-softmax + pooling of raw video rows. One block = one 128-row chunk.
// ---------------------------------------------------------------------------
__global__ __launch_bounds__(256) void flash_kernel(
    const float* __restrict__ video, const float* __restrict__ weff,
    const float* __restrict__ sbias,
    float* __restrict__ m_out, float* __restrict__ l_out,
    float* __restrict__ acc_out)
{
    const int blk  = blockIdx.x;
    const int p    = blk / NCHUNK;
    const int c    = blk % NCHUNK;
    const int wave = threadIdx.x >> 6;
    const int lane = threadIdx.x & 63;

    const float4* w4 = (const float4*)(weff + (size_t)p * VDIM);
    const float4 wv0 = w4[lane], wv1 = w4[lane + 64], wv2 = w4[lane + 128];
    const float sb = sbias[p];   // already includes 1/sqrt(1024)

    const float* base = video + ((size_t)p * SEQV + (size_t)c * CHUNK) * VDIM;

    float m = -1e30f, l = 0.f;
    float4 a0 = {0, 0, 0, 0}, a1 = {0, 0, 0, 0}, a2 = {0, 0, 0, 0};

    const int R = CHUNK / 4;            // 32 rows per wave, consecutive
    const float* rowp = base + (size_t)(wave * R) * VDIM;

    float4 u0 = ((const float4*)rowp)[lane];
    float4 u1 = ((const float4*)rowp)[lane + 64];
    float4 u2 = ((const float4*)rowp)[lane + 128];
    float4 x0 = ((const float4*)(rowp + VDIM))[lane];
    float4 x1 = ((const float4*)(rowp + VDIM))[lane + 64];
    float4 x2 = ((const float4*)(rowp + VDIM))[lane + 128];

    for (int r = 0; r < R; r += 2) {
        const float* nxtp = rowp + (r + 2 < R ? 2 * VDIM : 0);
        const float4 n0 = ((const float4*)nxtp)[lane];
        const float4 n1 = ((const float4*)nxtp)[lane + 64];
        const float4 n2 = ((const float4*)nxtp)[lane + 128];
        const float4 q0 = ((const float4*)(nxtp + VDIM))[lane];
        const float4 q1 = ((const float4*)(nxtp + VDIM))[lane + 64];
        const float4 q2 = ((const float4*)(nxtp + VDIM))[lane + 128];

        float d0 = u0.x * wv0.x + u0.y * wv0.y + u0.z * wv0.z + u0.w * wv0.w
                 + u1.x * wv1.x + u1.y * wv1.y + u1.z * wv1.z + u1.w * wv1.w
                 + u2.x * wv2.x + u2.y * wv2.y + u2.z * wv2.z + u2.w * wv2.w;
        float d1 = x0.x * wv0.x + x0.y * wv0.y + x0.z * wv0.z + x0.w * wv0.w
                 + x1.x * wv1.x + x1.y * wv1.y + x1.z * wv1.z + x1.w * wv1.w
                 + x2.x * wv2.x + x2.y * wv2.y + x2.z * wv2.z + x2.w * wv2.w;
#pragma unroll
        for (int off = 32; off; off >>= 1) {
            d0 += __shfl_xor(d0, off);
            d1 += __shfl_xor(d1, off);
        }
        const float s0 = d0 + sb, s1 = d1 + sb;
        const float mn = fmaxf(fmaxf(m, s0), s1);      // v_max3
        const float corr = __expf(m - mn);
        const float w0 = __expf(s0 - mn);
        const float w1 = __expf(s1 - mn);
        m = mn;
        l = l * corr + w0 + w1;
        a0.x = a0.x * corr + w0 * u0.x + w1 * x0.x;
        a0.y = a0.y * corr + w0 * u0.y + w1 * x0.y;
        a0.z = a0.z * corr + w0 * u0.z + w1 * x0.z;
        a0.w = a0.w * corr + w0 * u0.w + w1 * x0.w;
        a1.x = a1.x * corr + w0 * u1.x + w1 * x1.x;
        a1.y = a1.y * corr + w0 * u1.y + w1 * x1.y;
        a1.z = a1.z * corr + w0 * u1.z + w1 * x1.z;
        a1.w = a1.w * corr + w0 * u1.w + w1 * x1.w;
        a2.x = a2.x * corr + w0 * u2.x + w1 * x2.x;
        a2.y = a2.y * corr + w0 * u2.y + w1 * x2.y;
        a2.z = a2.z * corr + w0 * u2.z + w1 * x2.z;
        a2.w = a2.w * corr + w0 * u2.w + w1 * x2.w;

        u0 = n0; u1 = n1; u2 = n2;
        x0 = q0; x1 = q1; x2 = q2;
        rowp = nxtp;
    }

    __shared__ float s_m[4], s_l[4];
    __shared__ float s_acc[4][VDIM];
    if (lane == 0) { s_m[wave] = m; s_l[wave] = l; }
    float4* sa = (float4*)s_acc[wave];
    sa[lane] = a0; sa[lane + 64] = a1; sa[lane + 128] = a2;
    __syncthreads();

    const float M = fmaxf(fmaxf(s_m[0], s_m[1]), fmaxf(s_m[2], s_m[3]));
    const float c0 = __expf(s_m[0] - M), c1 = __expf(s_m[1] - M);
    const float c2 = __expf(s_m[2] - M), c3 = __expf(s_m[3] - M);
    const float L = s_l[0] * c0 + s_l[1] * c1 + s_l[2] * c2 + s_l[3] * c3;

    const int idx = p * NCHUNK + c;
    if (threadIdx.x == 0) { m_out[idx] = M; l_out[idx] = L; }
    float* ao = acc_out + (size_t)idx * VDIM;
    for (int d = threadIdx.x; d < VDIM; d += 256)
        ao[d] = s_acc[0][d] * c0 + s_acc[1][d] * c1 + s_acc[2][d] * c2 + s_acc[3][d] * c3;
}

// ---------------------------------------------------------------------------
// head_kernel: one block (1024 thr = 16 waves) per pair. Entire head:
//   coef -> vbar -> vh = Wvp@vbar+bvp -> pooled = Wv@vh ->
//   h1 = relu(W1@[pooled;qvec]+b1) -> out = softmax(W2@h1+b2+omask)
// ---------------------------------------------------------------------------
__global__ __launch_bounds__(1024) void head_kernel(
    const float* __restrict__ m_in, const float* __restrict__ l_in,
    const float* __restrict__ acc_in, const float* __restrict__ qvec_in,
    const float* __restrict__ Wvp, const float* __restrict__ bvp,
    const float* __restrict__ Wv,
    const float* __restrict__ W1, const float* __restrict__ b1,
    const float* __restrict__ W2, const float* __restrict__ b2,
    const float* __restrict__ omask, float* __restrict__ out)
{
    __shared__ float s_coef[NCHUNK];
    __shared__ float s_vbar[VDIM];
    __shared__ float s_vh[HID];
    __shared__ float s_x[HID2];     // pooled(512) ++ qvec(512)
    __shared__ float s_h1[HID];
    __shared__ float s_out[OUTC];

    const int p    = blockIdx.x;
    const int t    = threadIdx.x;
    const int wave = t >> 6;
    const int lane = t & 63;

    // softmax-combine coefficients across chunks (wave 0)
    if (wave == 0) {
        const float mv = (lane < NCHUNK) ? m_in[p * NCHUNK + lane] : -1e30f;
        float M = mv;
#pragma unroll
        for (int off = 32; off; off >>= 1) M = fmaxf(M, __shfl_xor(M, off));
        const float lv = (lane < NCHUNK) ? l_in[p * NCHUNK + lane] : 0.f;
        const float ce = (lane < NCHUNK) ? __expf(mv - M) : 0.f;
        float L = lv * ce;
#pragma unroll
        for (int off = 32; off; off >>= 1) L += __shfl_xor(L, off);
        if (lane < NCHUNK) s_coef[lane] = ce / L;
    }
    __syncthreads();

    // vbar[d] = sum_c coef[c] * acc[c][d]
    if (t < VDIM) {
        float a = 0.f;
#pragma unroll
        for (int c = 0; c < NCHUNK; ++c)
            a += s_coef[c] * acc_in[((size_t)p * NCHUNK + c) * VDIM + t];
        s_vbar[t] = a;
    }
    __syncthreads();

    // vh = Wvp @ vbar + bvp  (wave-per-row)
    for (int row = wave; row < HID; row += 16) {
        const float4* w4 = (const float4*)(Wvp + (size_t)row * VDIM);
        const float4* v4 = (const float4*)s_vbar;
        float acc = 0.f;
#pragma unroll
        for (int j = 0; j < 3; ++j) {
            float4 w = w4[lane + 64 * j], v = v4[lane + 64 * j];
            acc += w.x * v.x + w.y * v.y + w.z * v.z + w.w * v.w;
        }
#pragma unroll
        for (int off = 32; off; off >>= 1) acc += __shfl_xor(acc, off);
        if (lane == 0) s_vh[row] = acc + bvp[row];
    }
    __syncthreads();

    // pooled = Wv @ vh -> s_x[0:512]; qvec -> s_x[512:1024]
    for (int row = wave; row < HID; row += 16) {
        const float4* w4 = (const float4*)(Wv + (size_t)row * HID);
        const float4* v4 = (const float4*)s_vh;
        float acc = 0.f;
#pragma unroll
        for (int j = 0; j < 2; ++j) {
            float4 w = w4[lane + 64 * j], v = v4[lane + 64 * j];
            acc += w.x * v.x + w.y * v.y + w.z * v.z + w.w * v.w;
        }
#pragma unroll
        for (int off = 32; off; off >>= 1) acc += __shfl_xor(acc, off);
        if (lane == 0) s_x[row] = acc;
    }
    if (t < HID) s_x[HID + t] = qvec_in[p * HID + t];
    __syncthreads();

    // h1 = relu(W1 @ x + b1)
    for (int row = wave; row < HID; row += 16) {
        const float4* w4 = (const float4*)(W1 + (size_t)row * HID2);
        const float4* v4 = (const float4*)s_x;
        float acc = 0.f;
#pragma unroll
        for (int j = 0; j < 4; ++j) {
            float4 w = w4[lane + 64 * j], v = v4[lane + 64 * j];
            acc += w.x * v.x + w.y * v.y + w.z * v.z + w.w * v.w;
        }
#pragma unroll
        for (int off = 32; off; off >>= 1) acc += __shfl_xor(acc, off);
        if (lane == 0) s_h1[row] = fmaxf(acc + b1[row], 0.f);
    }
    __syncthreads();

    // logits + 5-way softmax (wave 0)
    if (wave == 0) {
        for (int o = 0; o < OUTC; ++o) {
            const float4* w4 = (const float4*)(W2 + (size_t)o * HID);
            const float4* v4 = (const float4*)s_h1;
            float acc = 0.f;
#pragma unroll
            for (int j = 0; j < 2; ++j) {
                float4 w = w4[lane + 64 * j], v = v4[lane + 64 * j];
                acc += w.x * v.x + w.y * v.y + w.z * v.z + w.w * v.w;
            }
#pragma unroll
            for (int off = 32; off; off >>= 1) acc += __shfl_xor(acc, off);
            if (lane == 0) s_out[o] = acc + b2[o] + omask[p * OUTC + o];
        }
        if (lane == 0) {
            float M = s_out[0];
            for (int o = 1; o < OUTC; ++o) M = fmaxf(M, s_out[o]);
            float e[OUTC], S = 0.f;
            for (int o = 0; o < OUTC; ++o) { e[o] = __expf(s_out[o] - M); S += e[o]; }
            const float inv = 1.f / S;
            for (int o = 0; o < OUTC; ++o) out[p * OUTC + o] = e[o] * inv;
        }
    }
}

// ---------------------------------------------------------------------------
extern "C" void kernel_launch(void* const* d_in, const int* in_sizes, int n_in,
                              void* d_out, int out_size, void* d_ws, size_t ws_size,
                              hipStream_t stream)
{
    const float* video = (const float*)d_in[0];
    const float* ques  = (const float*)d_in[1];
    // d_in[2] = ques_mask (all-ones; unused by the reference math)
    const float* omask = (const float*)d_in[3];
    const float* Wvp   = (const float*)d_in[4];
    const float* bvp   = (const float*)d_in[5];
    const float* Wqp   = (const float*)d_in[6];
    const float* bqp   = (const float*)d_in[7];
    const float* Wk    = (const float*)d_in[8];
    const float* Wv    = (const float*)d_in[9];
    const float* Wq    = (const float*)d_in[10];
    const float* W1    = (const float*)d_in[11];
    const float* b1    = (const float*)d_in[12];
    const float* W2    = (const float*)d_in[13];
    const float* b2    = (const float*)d_in[14];
    float* out = (float*)d_out;

    float* ws     = (float*)d_ws;
    float* qvec   = ws;                        // 80*512
    float* weff   = qvec + NPAIR * HID;        // 80*768
    float* sbias  = weff + NPAIR * VDIM;       // 80
    float* m_ws   = sbias + NPAIR;             // 80*16
    float* l_ws   = m_ws + NPAIR * NCHUNK;     // 80*16
    float* acc_ws = l_ws + NPAIR * NCHUNK;     // 80*16*768  (~4.3 MB total)

    hipLaunchKernelGGL(pre_kernel, dim3(NPAIR), dim3(1024), 0, stream,
                       ques, Wqp, bqp, Wq, Wk, Wvp, bvp, qvec, weff, sbias);
    hipLaunchKernelGGL(flash_kernel, dim3(NPAIR * NCHUNK), dim3(256), 0, stream,
                       video, weff, sbias, m_ws, l_ws, acc_ws);
    hipLaunchKernelGGL(head_kernel, dim3(NPAIR), dim3(1024), 0, stream,
                       m_ws, l_ws, acc_ws, qvec, Wvp, bvp, Wv, W1, b1, W2, b2,
                       omask, out);
}